// Round 13
// baseline (118.403 us; speedup 1.0000x reference)
//
#include <hip/hip_runtime.h>
#include <hip/hip_bf16.h>
#include <stdint.h>

typedef __bf16 bf16;
typedef __bf16 bf16x4 __attribute__((ext_vector_type(4)));
typedef __bf16 bf16x8 __attribute__((ext_vector_type(8)));
typedef float f32x4 __attribute__((ext_vector_type(4)));

#define B_ 4
#define N_ 1024
#define C_ 1024
#define H_ 16
#define MEG (1u << 20)

// ---- async global->LDS 16B ----
__device__ __forceinline__ uint32_t lds_off(const void* p) {
    return (uint32_t)(uintptr_t)p;  // low 32 bits of generic LDS ptr = LDS byte offset
}
__device__ __forceinline__ void g2l16(const void* g, uint32_t lds_byte) {
    __builtin_amdgcn_global_load_lds(
        (const __attribute__((address_space(1))) unsigned int*)(uintptr_t)g,
        (__attribute__((address_space(3))) unsigned int*)(uintptr_t)lds_byte,
        16, 0, 0);
}

// ---------------------------------------------------------------------------
// Fused prep: blocks [0,3072) = f32->bf16 weight converts (Wq0,Wq1,Wp0,Wp1);
// blocks [3072,4096) = x (B,N,C) f32 -> xT (B,C,N) bf16 via 64x64 LDS tiles.
// ---------------------------------------------------------------------------
__global__ __launch_bounds__(256) void prep_k(
    const float* __restrict__ x, bf16* __restrict__ xT,
    const float* __restrict__ s0, bf16* __restrict__ d0,
    const float* __restrict__ s1, bf16* __restrict__ d1,
    const float* __restrict__ s2, bf16* __restrict__ d2,
    const float* __restrict__ s3, bf16* __restrict__ d3)
{
    __shared__ bf16 t[64][66];
    const int bid = blockIdx.x;
    const int tid = threadIdx.x;
    if (bid < 3072) {
        const float* s; bf16* d; int base;
        if (bid < 512)       { s = s0; d = d0; base = 0; }
        else if (bid < 2048) { s = s1; d = d1; base = 512; }
        else if (bid < 2560) { s = s2; d = d2; base = 2048; }
        else                 { s = s3; d = d3; base = 2560; }
        int i = ((bid - base) * 256 + tid) * 8;
        float4 a = *(const float4*)(s + i);
        float4 b = *(const float4*)(s + i + 4);
        bf16x8 r;
        r[0] = (bf16)a.x; r[1] = (bf16)a.y; r[2] = (bf16)a.z; r[3] = (bf16)a.w;
        r[4] = (bf16)b.x; r[5] = (bf16)b.y; r[6] = (bf16)b.z; r[7] = (bf16)b.w;
        *(bf16x8*)(d + i) = r;
        return;
    }
    const int idx = bid - 3072;
    const int c0 = (idx & 15) * 64, n0 = ((idx >> 4) & 15) * 64, b = idx >> 8;
    {
        int nl = tid >> 2, seg = tid & 3;
        const float* src = x + ((size_t)b * N_ + n0 + nl) * C_ + c0 + seg * 16;
#pragma unroll
        for (int i = 0; i < 4; ++i) {
            float4 v = *(const float4*)(src + i * 4);
            t[nl][seg * 16 + i * 4 + 0] = (bf16)v.x;
            t[nl][seg * 16 + i * 4 + 1] = (bf16)v.y;
            t[nl][seg * 16 + i * 4 + 2] = (bf16)v.z;
            t[nl][seg * 16 + i * 4 + 3] = (bf16)v.w;
        }
    }
    __syncthreads();
    {
        int cl = tid >> 2, seg = tid & 3;
        bf16* dst = xT + ((size_t)b * C_ + c0 + cl) * N_ + n0 + seg * 16;
        bf16x8 o0, o1;
#pragma unroll
        for (int j = 0; j < 8; ++j) o0[j] = t[seg * 16 + j][cl];
#pragma unroll
        for (int j = 0; j < 8; ++j) o1[j] = t[seg * 16 + 8 + j][cl];
        *(bf16x8*)dst = o0;
        *(bf16x8*)(dst + 8) = o1;
    }
}

// ---------------------------------------------------------------------------
// Phase-split NT GEMM for the wide qkv matmul: BM=256, BN=192, BK=64,
// 512 thr (8 waves = 2M x 4N; wave tile 128x48; acc 8x3 f32x4).
// Grid (3072/192=16) x (4096/256=16) = 256 blocks = 1/CU, 100% coverage.
// Per K-tile: 4 phases (mh,kk); each = {7 ds_read_b128 || staging ->
// s_barrier -> lgkmcnt(0) -> setprio(1) -> 12 MFMA -> setprio(0) -> barrier}.
// Staging of tile u+1 front-loaded into phases q0 (A, 4 g2l16) / q1 (B, 3),
// so the end-of-tile vmcnt(0) waits on loads issued 2-3 phases earlier.
// LDS: 2 bufs x (A 32KB + B 24KB) = 112 KB, K-tile-granular double buffer.
// VSPLIT: cols >= 2048 (V third) written transposed to vT (16-col frags are
// region-uniform: 48*wn+16*ni is 16-aligned, 2048 is 16-aligned).
// ---------------------------------------------------------------------------
template <int BIAS, bool OF32, bool VSPLIT>
__global__ __launch_bounds__(512) void gemm256_k(
    const bf16* __restrict__ A, const bf16* __restrict__ Bm,
    const float* __restrict__ bias, void* __restrict__ Cv,
    bf16* __restrict__ vT, int M, int Nn, int K)
{
    __shared__ bf16 smem[2 * 28672];   // 112 KB

    const int tid = threadIdx.x;
    const int lane = tid & 63, wid = tid >> 6;
    const int lr = lane & 15, lg = lane >> 4;
    const int wm = wid >> 2, wn = wid & 3;
    const int m0 = blockIdx.y * 256, n0 = blockIdx.x * 192;

    const uint32_t lds0 = lds_off(&smem[0]);

    auto stageA = [&](int u) {
        const uint32_t dst = lds0 + (u & 1) * 57344u;
#pragma unroll
        for (int hh = 0; hh < 4; ++hh) {          // 2048 chunks, 4/thread
            int c = tid + hh * 512;
            int r = c >> 3, ch = c & 7;
            int sch = ch ^ (r & 7);
            g2l16(A + (size_t)(m0 + r) * K + u * 64 + sch * 8, dst + c * 16u);
        }
    };
    auto stageB = [&](int u) {
        const uint32_t dst = lds0 + (u & 1) * 57344u + 32768u;
#pragma unroll
        for (int hh = 0; hh < 3; ++hh) {          // 1536 chunks, 3/thread
            int c = tid + hh * 512;
            int r = c >> 3, ch = c & 7;
            int sch = ch ^ (r & 7);
            g2l16(Bm + (size_t)(n0 + r) * K + u * 64 + sch * 8, dst + c * 16u);
        }
    };

    f32x4 acc[8][3];
#pragma unroll
    for (int i = 0; i < 8; ++i)
#pragma unroll
        for (int j = 0; j < 3; ++j) { f32x4 z = {0.f,0.f,0.f,0.f}; acc[i][j] = z; }

    stageA(0);
    stageB(0);
    asm volatile("s_waitcnt vmcnt(0)" ::: "memory");
    __builtin_amdgcn_s_barrier();

    const int nt = K >> 6;   // 16
    for (int u = 0; u < nt; ++u) {
        const bf16* As = smem + (u & 1) * 28672;
        const bf16* Bs = As + 16384;
#pragma unroll
        for (int q = 0; q < 4; ++q) {
            const int mh = q >> 1, kk = q & 1;
            bf16x8 af[4], bfr[3];
#pragma unroll
            for (int mi = 0; mi < 4; ++mi) {
                int row = wm * 128 + mh * 64 + mi * 16 + lr;
                int slot = (kk * 4 + lg) ^ (row & 7);
                af[mi] = *(const bf16x8*)(As + row * 64 + slot * 8);
            }
#pragma unroll
            for (int ni = 0; ni < 3; ++ni) {
                int row = wn * 48 + ni * 16 + lr;
                int slot = (kk * 4 + lg) ^ (row & 7);
                bfr[ni] = *(const bf16x8*)(Bs + row * 64 + slot * 8);
            }
            if (q == 0 && u + 1 < nt) stageA(u + 1);   // front-loaded prefetch
            if (q == 1 && u + 1 < nt) stageB(u + 1);
            __builtin_amdgcn_s_barrier();
            asm volatile("s_waitcnt lgkmcnt(0)" ::: "memory");
            __builtin_amdgcn_s_setprio(1);
#pragma unroll
            for (int mi = 0; mi < 4; ++mi)
#pragma unroll
                for (int ni = 0; ni < 3; ++ni)
                    acc[mh * 4 + mi][ni] = __builtin_amdgcn_mfma_f32_16x16x32_bf16(
                        af[mi], bfr[ni], acc[mh * 4 + mi][ni], 0, 0, 0);
            __builtin_amdgcn_s_setprio(0);
            if (q == 3)   // 2-3 phases after issue -> effectively counted
                asm volatile("s_waitcnt vmcnt(0)" ::: "memory");
            __builtin_amdgcn_s_barrier();
        }
    }

    // epilogue (C/D: col=lane&15, row=(lane>>4)*4+r)
#pragma unroll
    for (int mi = 0; mi < 8; ++mi)
#pragma unroll
        for (int ni = 0; ni < 3; ++ni) {
            int col = n0 + wn * 48 + ni * 16 + lr;
            if constexpr (VSPLIT) {
                if (col >= 2048) {   // V third -> transposed vT[b][dl][n]
                    float bv = bias[col];
                    bf16x4 w;
#pragma unroll
                    for (int r = 0; r < 4; ++r) w[r] = (bf16)(acc[mi][ni][r] + bv);
                    int row0 = m0 + wm * 128 + mi * 16 + lg * 4;
                    int bb = row0 >> 10, n = row0 & 1023;
                    *(bf16x4*)(vT + (size_t)bb * MEG +
                               (size_t)(col - 2048) * 1024 + n) = w;
                    continue;
                }
            }
#pragma unroll
            for (int r = 0; r < 4; ++r) {
                int row = m0 + wm * 128 + mi * 16 + lg * 4 + r;
                float bv = (BIAS == 0) ? bias[row] : bias[col];
                float v = acc[mi][ni][r] + bv;
                if constexpr (OF32)
                    ((float*)Cv)[(size_t)row * Nn + col] = v;
                else
                    ((bf16*)Cv)[(size_t)row * Nn + col] = (bf16)v;
            }
        }
}

// ---------------------------------------------------------------------------
// NT GEMM, 128x64 tile, BK=64, 256 thr (4 waves, 64x32 wave tiles) — the
// small-GEMM variant (2 blocks/CU so cross-block overlap hides drains).
// ---------------------------------------------------------------------------
template <int BIAS, bool OF32>
__global__ __launch_bounds__(256) void gemm64_k(
    const bf16* __restrict__ A, const bf16* __restrict__ Bm,
    const float* __restrict__ bias, void* __restrict__ Cv,
    int M, int Nn, int K, long long sA, long long sB, long long sC)
{
    __shared__ bf16 smem[2][192 * 64];  // rows 0-127: A, rows 128-191: B

    const int tid = threadIdx.x;
    const int lane = tid & 63, wid = tid >> 6;
    const int lr = lane & 15, lg = lane >> 4;
    const int wr = wid >> 1, wc = wid & 1;
    const int m0 = blockIdx.y * 128, n0 = blockIdx.x * 64;

    const bf16* Ab = A + (size_t)blockIdx.z * sA;
    const bf16* Bb = Bm + (size_t)blockIdx.z * sB;

    const uint32_t a_lds0 = lds_off(&smem[0][0]);
    const uint32_t b_lds0 = a_lds0 + 128 * 64 * 2;
    const uint32_t bufstride = 192 * 64 * 2;

    auto stage = [&](int kt, int buf) {
#pragma unroll
        for (int h = 0; h < 4; ++h) {
            int it = tid + h * 256;
            int r = it >> 3, ch = it & 7;
            int sch = ch ^ (r & 7);
            g2l16(Ab + (size_t)(m0 + r) * K + kt * 64 + sch * 8,
                  a_lds0 + buf * bufstride + it * 16);
        }
#pragma unroll
        for (int h = 0; h < 2; ++h) {
            int it = tid + h * 256;
            int r = it >> 3, ch = it & 7;
            int sch = ch ^ (r & 7);
            g2l16(Bb + (size_t)(n0 + r) * K + kt * 64 + sch * 8,
                  b_lds0 + buf * bufstride + it * 16);
        }
    };

    f32x4 acc[4][2];
#pragma unroll
    for (int i = 0; i < 4; ++i)
#pragma unroll
        for (int j = 0; j < 2; ++j) { f32x4 z = {0.f,0.f,0.f,0.f}; acc[i][j] = z; }

    stage(0, 0);
    __syncthreads();

    const int nt = K >> 6;
    for (int t = 0; t < nt; ++t) {
        int buf = t & 1;
        if (t + 1 < nt) stage(t + 1, buf ^ 1);
        const bf16* As = &smem[buf][0];
        const bf16* Bs = &smem[buf][128 * 64];
#pragma unroll
        for (int s = 0; s < 2; ++s) {
            bf16x8 af[4], bfr[2];
#pragma unroll
            for (int mi = 0; mi < 4; ++mi) {
                int row = wr * 64 + mi * 16 + lr;
                int slot = (s * 4 + lg) ^ (row & 7);
                af[mi] = *(const bf16x8*)(As + row * 64 + slot * 8);
            }
#pragma unroll
            for (int ni = 0; ni < 2; ++ni) {
                int row = wc * 32 + ni * 16 + lr;
                int slot = (s * 4 + lg) ^ (row & 7);
                bfr[ni] = *(const bf16x8*)(Bs + row * 64 + slot * 8);
            }
#pragma unroll
            for (int mi = 0; mi < 4; ++mi)
#pragma unroll
                for (int ni = 0; ni < 2; ++ni)
                    acc[mi][ni] = __builtin_amdgcn_mfma_f32_16x16x32_bf16(
                        af[mi], bfr[ni], acc[mi][ni], 0, 0, 0);
        }
        __syncthreads();
    }

#pragma unroll
    for (int mi = 0; mi < 4; ++mi)
#pragma unroll
        for (int ni = 0; ni < 2; ++ni)
#pragma unroll
            for (int r = 0; r < 4; ++r) {
                int row = m0 + wr * 64 + mi * 16 + lg * 4 + r;
                int col = n0 + wc * 32 + ni * 16 + lr;
                float bv = (BIAS == 0) ? bias[row] : bias[col];
                float v = acc[mi][ni][r] + bv;
                if constexpr (OF32)
                    ((float*)Cv + (size_t)blockIdx.z * sC)[(size_t)row * Nn + col] = v;
                else
                    ((bf16*)Cv + (size_t)blockIdx.z * sC)[(size_t)row * Nn + col] = (bf16)v;
            }
}

// ---------------------------------------------------------------------------
// Attention (unchanged from round 11/12): qkv (Q,K) + vT -> aoT (B,C,N).
// 256 thr = 4 waves; each wave owns 32 q-rows (two 16-row subtiles A/B).
// ---------------------------------------------------------------------------
__global__ __launch_bounds__(256) void attn_k(
    const bf16* __restrict__ qkv, const bf16* __restrict__ vT,
    bf16* __restrict__ aoT)
{
    __shared__ bf16 Ks[2][4096];
    __shared__ bf16 Vs[2][4096];
    __shared__ bf16 pbuf[4][2048];

    const int tid = threadIdx.x;
    const int lane = tid & 63, wid = tid >> 6;
    const int lr = lane & 15, lg = lane >> 4;
    const int bid = blockIdx.x;
    const int qt = bid >> 6, hb = bid & 63;
    const int b = hb >> 4, h = hb & 15;
    const int qrow0 = qt * 128 + wid * 32;
    const int hoff = h * 64;
    const bf16* qkvb = qkv + (size_t)b * (N_ * 3 * C_);
    const bf16* vTb  = vT + (size_t)b * MEG;

    bf16x8 qfA[2], qfB[2];
#pragma unroll
    for (int kk = 0; kk < 2; ++kk) {
        qfA[kk] = *(const bf16x8*)(qkvb + (size_t)(qrow0 + lr) * 3072 +
                                   hoff + kk * 32 + lg * 8);
        qfB[kk] = *(const bf16x8*)(qkvb + (size_t)(qrow0 + 16 + lr) * 3072 +
                                   hoff + kk * 32 + lg * 8);
#pragma unroll
        for (int j = 0; j < 8; ++j) {
            qfA[kk][j] = (bf16)((float)qfA[kk][j] * 0.18033688f);
            qfB[kk][j] = (bf16)((float)qfB[kk][j] * 0.18033688f);
        }
    }

    const uint32_t ks0 = lds_off(&Ks[0][0]);
    const uint32_t vs0 = lds_off(&Vs[0][0]);

    auto stageK = [&](int kt, int buf) {
#pragma unroll
        for (int hh = 0; hh < 2; ++hh) {
            int it = tid + hh * 256;
            int key = it >> 3, ch = it & 7;
            int sch = ch ^ (key & 7);
            g2l16(qkvb + (size_t)(kt * 64 + key) * 3072 + C_ + hoff + sch * 8,
                  ks0 + buf * 8192 + it * 16);
        }
    };
    auto stageV = [&](int kt, int buf) {
#pragma unroll
        for (int hh = 0; hh < 2; ++hh) {
            int it = tid + hh * 256;
            int d = it >> 3, ch = it & 7;
            int sch = ch ^ (d & 7);
            g2l16(vTb + (size_t)(hoff + d) * 1024 + kt * 64 + sch * 8,
                  vs0 + buf * 8192 + it * 16);
        }
    };

    float lsumA = 0.f, lsumB = 0.f;
    f32x4 oA[4], oB[4];
#pragma unroll
    for (int i = 0; i < 4; ++i) {
        f32x4 z = {0.f,0.f,0.f,0.f};
        oA[i] = z; oB[i] = z;
    }

    char* prowA = (char*)&pbuf[wid][0] + lr * 128;
    char* prowB = (char*)&pbuf[wid][0] + (16 + lr) * 128;
    const int swz = (lr & 7) << 4;

    stageK(0, 0);
    stageV(0, 0);
    __syncthreads();

    for (int kt = 0; kt < 16; ++kt) {
        int buf = kt & 1;
        if (kt + 1 < 16) {
            stageK(kt + 1, buf ^ 1);
            stageV(kt + 1, buf ^ 1);
        }

        f32x4 sA[4], sB[4];
        __builtin_amdgcn_s_setprio(1);
#pragma unroll
        for (int st = 0; st < 4; ++st) {
            f32x4 zA = {0.f, 0.f, 0.f, 0.f};
            f32x4 zB = {0.f, 0.f, 0.f, 0.f};
#pragma unroll
            for (int kk = 0; kk < 2; ++kk) {
                int row = st * 16 + lr;
                int slot = (kk * 4 + lg) ^ (row & 7);
                bf16x8 kf = *(const bf16x8*)(&Ks[buf][row * 64 + slot * 8]);
                zA = __builtin_amdgcn_mfma_f32_16x16x32_bf16(kf, qfA[kk], zA, 0, 0, 0);
                zB = __builtin_amdgcn_mfma_f32_16x16x32_bf16(kf, qfB[kk], zB, 0, 0, 0);
            }
            sA[st] = zA; sB[st] = zB;
        }
        __builtin_amdgcn_s_setprio(0);

#pragma unroll
        for (int st = 0; st < 4; ++st) {
            bf16x4 wA, wB;
#pragma unroll
            for (int r = 0; r < 4; ++r) {
                float eA = __builtin_amdgcn_exp2f(sA[st][r]);
                float eB = __builtin_amdgcn_exp2f(sB[st][r]);
                wA[r] = (bf16)eA; lsumA += eA;
                wB[r] = (bf16)eB; lsumB += eB;
            }
            *(bf16x4*)(prowA + ((st * 32 + lg * 8) ^ swz)) = wA;
            *(bf16x4*)(prowB + ((st * 32 + lg * 8) ^ swz)) = wB;
        }

        bf16x8 pfA[2], pfB[2];
        pfA[0] = *(const bf16x8*)(prowA + ((lg * 16) ^ swz));
        pfA[1] = *(const bf16x8*)(prowA + ((64 + lg * 16) ^ swz));
        pfB[0] = *(const bf16x8*)(prowB + ((lg * 16) ^ swz));
        pfB[1] = *(const bf16x8*)(prowB + ((64 + lg * 16) ^ swz));

        __builtin_amdgcn_s_setprio(1);
#pragma unroll
        for (int dt = 0; dt < 4; ++dt) {
            int row = dt * 16 + lr;
            bf16x8 v0 = *(const bf16x8*)(&Vs[buf][row * 64 + ((lg ^ (lr & 7)) * 8)]);
            bf16x8 v1 = *(const bf16x8*)(&Vs[buf][row * 64 + (((4 + lg) ^ (lr & 7)) * 8)]);
            oA[dt] = __builtin_amdgcn_mfma_f32_16x16x32_bf16(pfA[0], v0, oA[dt], 0, 0, 0);
            oA[dt] = __builtin_amdgcn_mfma_f32_16x16x32_bf16(pfA[1], v1, oA[dt], 0, 0, 0);
            oB[dt] = __builtin_amdgcn_mfma_f32_16x16x32_bf16(pfB[0], v0, oB[dt], 0, 0, 0);
            oB[dt] = __builtin_amdgcn_mfma_f32_16x16x32_bf16(pfB[1], v1, oB[dt], 0, 0, 0);
        }
        __builtin_amdgcn_s_setprio(0);

        __syncthreads();
    }

    lsumA += __shfl_xor(lsumA, 16, 64);
    lsumA += __shfl_xor(lsumA, 32, 64);
    lsumB += __shfl_xor(lsumB, 16, 64);
    lsumB += __shfl_xor(lsumB, 32, 64);
    float rtotA = 1.0f / lsumA, rtotB = 1.0f / lsumB;
    float rcpoA[4], rcpoB[4];
#pragma unroll
    for (int r = 0; r < 4; ++r) {
        rcpoA[r] = __shfl(rtotA, lg * 4 + r, 64);
        rcpoB[r] = __shfl(rtotB, lg * 4 + r, 64);
    }

#pragma unroll
    for (int dt = 0; dt < 4; ++dt) {
        bf16x4 ovA, ovB;
#pragma unroll
        for (int r = 0; r < 4; ++r) {
            ovA[r] = (bf16)(oA[dt][r] * rcpoA[r]);
            ovB[r] = (bf16)(oB[dt][r] * rcpoB[r]);
        }
        size_t c = (size_t)b * C_ + hoff + dt * 16 + lr;
        *(bf16x4*)(aoT + c * N_ + qrow0 + lg * 4) = ovA;
        *(bf16x4*)(aoT + c * N_ + qrow0 + 16 + lg * 4) = ovB;
    }
}

// ---------------------------------------------------------------------------
// Workspace (bf16 elems; 26M = 52MB, proven budget):
//   xT   @  0M (4M)  gemm1 B; dead after gemm1 -> vT (written by gemm2)
//   Wq0b @  4M (1M)  dead after gemm1
//   Wq1b @  5M (3M)  dead after gemm2
//   Wp0b @  8M (1M)
//   Wp1b @  9M (1M)
//   y1   @ 10M (4M)  gemm1 out; dead after gemm2 -> aoT
//   y2   @ 14M (12M) qkv Q,K (V third unwritten); dead after attn -> z1
// ---------------------------------------------------------------------------
extern "C" void kernel_launch(void* const* d_in, const int* in_sizes, int n_in,
                              void* d_out, int out_size, void* d_ws, size_t ws_size,
                              hipStream_t stream) {
    (void)in_sizes; (void)n_in; (void)out_size; (void)ws_size;
    const float* x   = (const float*)d_in[0];
    const float* Wq0 = (const float*)d_in[1];
    const float* bq0 = (const float*)d_in[2];
    const float* Wq1 = (const float*)d_in[3];
    const float* bq1 = (const float*)d_in[4];
    const float* Wp0 = (const float*)d_in[5];
    const float* bp0 = (const float*)d_in[6];
    const float* Wp1 = (const float*)d_in[7];
    const float* bp1 = (const float*)d_in[8];

    bf16* ws   = (bf16*)d_ws;
    bf16* xT   = ws;
    bf16* Wq0b = ws + 4 * MEG;
    bf16* Wq1b = ws + 5 * MEG;
    bf16* Wp0b = ws + 8 * MEG;
    bf16* Wp1b = ws + 9 * MEG;
    bf16* y1   = ws + 10 * MEG;
    bf16* y2   = ws + 14 * MEG;
    bf16* vT   = xT;   // xT dead after gemm1; vT written by gemm2
    bf16* aoT  = y1;   // y1 dead after gemm2
    bf16* z1   = y2;   // y2 dead after attn
    float* outp = (float*)d_out;

    const long long s1M = (long long)N_ * C_;

    prep_k<<<dim3(4096), 256, 0, stream>>>(x, xT, Wq0, Wq0b, Wq1, Wq1b,
                                           Wp0, Wp0b, Wp1, Wp1b);

    // y1[b,m,c] = sum_n Wq0[m,n] xT[b,c,n] + bq0[m]   (512 blocks = 2/CU)
    gemm64_k<0, false><<<dim3(16, 8, 4), 256, 0, stream>>>(
        Wq0b, xT, bq0, y1, 1024, 1024, 1024, 0LL, s1M, s1M);
    // y2[(b,n),d] = sum_c y1[(b,n),c] Wq1[d,c] + bq1[d]; V third -> vT
    // phase-split 256x192 tiles, 256 blocks = 1/CU full coverage
    gemm256_k<1, false, true><<<dim3(16, 16), 512, 0, stream>>>(
        y1, Wq1b, bq1, y2, vT, 4096, 3072, 1024);
    // attention -> aoT (B,C,N)
    attn_k<<<dim3(512), 256, 0, stream>>>(y2, vT, aoT);
    // z1[b,m,c] = sum_n Wp0[m,n] aoT[b,c,n] + bp0[m]   (512 blocks = 2/CU)
    gemm64_k<0, false><<<dim3(16, 8, 4), 256, 0, stream>>>(
        Wp0b, aoT, bp0, z1, 1024, 1024, 1024, 0LL, s1M, s1M);
    // out[(b,n),d] = sum_c z1[(b,n),c] Wp1[d,c] + bp1[d] (512 blocks = 2/CU)
    gemm64_k<1, true><<<dim3(16, 32, 1), 256, 0, stream>>>(
        z1, Wp1b, bp1, outp, 4096, 1024, 1024, 0LL, 0LL, 0LL);
}

// Round 14
// 113.821 us; speedup vs baseline: 1.0403x; 1.0403x over previous
//
#include <hip/hip_runtime.h>
#include <hip/hip_bf16.h>
#include <stdint.h>

typedef __bf16 bf16;
typedef __bf16 bf16x4 __attribute__((ext_vector_type(4)));
typedef __bf16 bf16x8 __attribute__((ext_vector_type(8)));
typedef float f32x4 __attribute__((ext_vector_type(4)));

#define B_ 4
#define N_ 1024
#define C_ 1024
#define H_ 16
#define MEG (1u << 20)

// ---- async global->LDS 16B ----
__device__ __forceinline__ uint32_t lds_off(const void* p) {
    return (uint32_t)(uintptr_t)p;  // low 32 bits of generic LDS ptr = LDS byte offset
}
__device__ __forceinline__ void g2l16(const void* g, uint32_t lds_byte) {
    __builtin_amdgcn_global_load_lds(
        (const __attribute__((address_space(1))) unsigned int*)(uintptr_t)g,
        (__attribute__((address_space(3))) unsigned int*)(uintptr_t)lds_byte,
        16, 0, 0);
}

// ---------------------------------------------------------------------------
// Fused prep: blocks [0,3072) = f32->bf16 weight converts (Wq0,Wq1,Wp0,Wp1);
// blocks [3072,4096) = x (B,N,C) f32 -> xT (B,C,N) bf16 via 64x64 LDS tiles.
// ---------------------------------------------------------------------------
__global__ __launch_bounds__(256) void prep_k(
    const float* __restrict__ x, bf16* __restrict__ xT,
    const float* __restrict__ s0, bf16* __restrict__ d0,
    const float* __restrict__ s1, bf16* __restrict__ d1,
    const float* __restrict__ s2, bf16* __restrict__ d2,
    const float* __restrict__ s3, bf16* __restrict__ d3)
{
    __shared__ bf16 t[64][66];
    const int bid = blockIdx.x;
    const int tid = threadIdx.x;
    if (bid < 3072) {
        const float* s; bf16* d; int base;
        if (bid < 512)       { s = s0; d = d0; base = 0; }
        else if (bid < 2048) { s = s1; d = d1; base = 512; }
        else if (bid < 2560) { s = s2; d = d2; base = 2048; }
        else                 { s = s3; d = d3; base = 2560; }
        int i = ((bid - base) * 256 + tid) * 8;
        float4 a = *(const float4*)(s + i);
        float4 b = *(const float4*)(s + i + 4);
        bf16x8 r;
        r[0] = (bf16)a.x; r[1] = (bf16)a.y; r[2] = (bf16)a.z; r[3] = (bf16)a.w;
        r[4] = (bf16)b.x; r[5] = (bf16)b.y; r[6] = (bf16)b.z; r[7] = (bf16)b.w;
        *(bf16x8*)(d + i) = r;
        return;
    }
    const int idx = bid - 3072;
    const int c0 = (idx & 15) * 64, n0 = ((idx >> 4) & 15) * 64, b = idx >> 8;
    {
        int nl = tid >> 2, seg = tid & 3;
        const float* src = x + ((size_t)b * N_ + n0 + nl) * C_ + c0 + seg * 16;
#pragma unroll
        for (int i = 0; i < 4; ++i) {
            float4 v = *(const float4*)(src + i * 4);
            t[nl][seg * 16 + i * 4 + 0] = (bf16)v.x;
            t[nl][seg * 16 + i * 4 + 1] = (bf16)v.y;
            t[nl][seg * 16 + i * 4 + 2] = (bf16)v.z;
            t[nl][seg * 16 + i * 4 + 3] = (bf16)v.w;
        }
    }
    __syncthreads();
    {
        int cl = tid >> 2, seg = tid & 3;
        bf16* dst = xT + ((size_t)b * C_ + c0 + cl) * N_ + n0 + seg * 16;
        bf16x8 o0, o1;
#pragma unroll
        for (int j = 0; j < 8; ++j) o0[j] = t[seg * 16 + j][cl];
#pragma unroll
        for (int j = 0; j < 8; ++j) o1[j] = t[seg * 16 + 8 + j][cl];
        *(bf16x8*)dst = o0;
        *(bf16x8*)(dst + 8) = o1;
    }
}

// ---------------------------------------------------------------------------
// NT GEMM (all-bf16), 128x128 tile, BK=64, 512 thr (8 waves, 64x32 wave
// tiles). Proven 2-phase double-buffer via global_load_lds + XOR chunk
// swizzle. Used for the wide qkv GEMM (768 blocks = 3/CU).
// VSPLIT: output cols in [2048,3072) written transposed to vT.
// ---------------------------------------------------------------------------
template <int BIAS, bool OF32, bool VSPLIT>
__global__ __launch_bounds__(512) void gemm_k(
    const bf16* __restrict__ A, const bf16* __restrict__ Bm,
    const float* __restrict__ bias, void* __restrict__ Cv,
    bf16* __restrict__ vT,
    int M, int Nn, int K, long long sA, long long sB, long long sC)
{
    __shared__ bf16 smem[2][2][128 * 64];  // [buf][A/B][row*64 + k]

    const int tid = threadIdx.x;
    const int lane = tid & 63, wid = tid >> 6;
    const int lr = lane & 15, lg = lane >> 4;
    const int wr = wid >> 2, wc = wid & 3;
    const int m0 = blockIdx.y * 128, n0 = blockIdx.x * 128;

    const bf16* Ab = A + (size_t)blockIdx.z * sA;
    const bf16* Bb = Bm + (size_t)blockIdx.z * sB;

    const uint32_t a_lds0 = lds_off(&smem[0][0][0]);
    const uint32_t b_lds0 = lds_off(&smem[0][1][0]);
    const uint32_t bufstride = 2 * 128 * 64 * 2;  // bytes buf0 -> buf1

    auto stage = [&](int kt, int buf) {
#pragma unroll
        for (int half = 0; half < 2; ++half) {
            int it = tid + half * 512;
            int r = it >> 3, ch = it & 7;
            int sch = ch ^ (r & 7);
            g2l16(Ab + (size_t)(m0 + r) * K + kt * 64 + sch * 8,
                  a_lds0 + buf * bufstride + it * 16);
            g2l16(Bb + (size_t)(n0 + r) * K + kt * 64 + sch * 8,
                  b_lds0 + buf * bufstride + it * 16);
        }
    };

    f32x4 acc[4][2];
#pragma unroll
    for (int i = 0; i < 4; ++i)
#pragma unroll
        for (int j = 0; j < 2; ++j) { f32x4 z = {0.f,0.f,0.f,0.f}; acc[i][j] = z; }

    stage(0, 0);
    __syncthreads();

    const int nt = K >> 6;
    for (int t = 0; t < nt; ++t) {
        int buf = t & 1;
        if (t + 1 < nt) stage(t + 1, buf ^ 1);
        const bf16* As = &smem[buf][0][0];
        const bf16* Bs = &smem[buf][1][0];
#pragma unroll
        for (int s = 0; s < 2; ++s) {
            bf16x8 af[4], bfr[2];
#pragma unroll
            for (int mi = 0; mi < 4; ++mi) {
                int row = wr * 64 + mi * 16 + lr;
                int slot = (s * 4 + lg) ^ (row & 7);
                af[mi] = *(const bf16x8*)(As + row * 64 + slot * 8);
            }
#pragma unroll
            for (int ni = 0; ni < 2; ++ni) {
                int row = wc * 32 + ni * 16 + lr;
                int slot = (s * 4 + lg) ^ (row & 7);
                bfr[ni] = *(const bf16x8*)(Bs + row * 64 + slot * 8);
            }
#pragma unroll
            for (int mi = 0; mi < 4; ++mi)
#pragma unroll
                for (int ni = 0; ni < 2; ++ni)
                    acc[mi][ni] = __builtin_amdgcn_mfma_f32_16x16x32_bf16(
                        af[mi], bfr[ni], acc[mi][ni], 0, 0, 0);
        }
        __syncthreads();
    }

    // epilogue (C/D: col=lane&15, row=(lane>>4)*4+r)
#pragma unroll
    for (int mi = 0; mi < 4; ++mi)
#pragma unroll
        for (int ni = 0; ni < 2; ++ni) {
            int col = n0 + wc * 32 + ni * 16 + lr;
            if constexpr (VSPLIT) {
                if (col >= 2048) {   // V third -> transposed vT[b][dl][n]
                    float bv = bias[col];
                    bf16x4 w;
#pragma unroll
                    for (int r = 0; r < 4; ++r) w[r] = (bf16)(acc[mi][ni][r] + bv);
                    int row0 = m0 + wr * 64 + mi * 16 + lg * 4;
                    int bb = row0 >> 10, n = row0 & 1023;
                    *(bf16x4*)(vT + (size_t)bb * MEG +
                               (size_t)(col - 2048) * 1024 + n) = w;
                    continue;
                }
            }
#pragma unroll
            for (int r = 0; r < 4; ++r) {
                int row = m0 + wr * 64 + mi * 16 + lg * 4 + r;
                float bv = (BIAS == 0) ? bias[row] : bias[col];
                float v = acc[mi][ni][r] + bv;
                if constexpr (OF32)
                    ((float*)Cv + (size_t)blockIdx.z * sC)[(size_t)row * Nn + col] = v;
                else
                    ((bf16*)Cv + (size_t)blockIdx.z * sC)[(size_t)row * Nn + col] = (bf16)v;
            }
        }
}

// ---------------------------------------------------------------------------
// NT GEMM, 128x64 tile, BK=64, 256 thr (4 waves, 64x32 wave tiles) — the
// small-GEMM variant (2 blocks/CU so cross-block overlap hides drains).
// ---------------------------------------------------------------------------
template <int BIAS, bool OF32>
__global__ __launch_bounds__(256) void gemm64_k(
    const bf16* __restrict__ A, const bf16* __restrict__ Bm,
    const float* __restrict__ bias, void* __restrict__ Cv,
    int M, int Nn, int K, long long sA, long long sB, long long sC)
{
    __shared__ bf16 smem[2][192 * 64];  // rows 0-127: A, rows 128-191: B

    const int tid = threadIdx.x;
    const int lane = tid & 63, wid = tid >> 6;
    const int lr = lane & 15, lg = lane >> 4;
    const int wr = wid >> 1, wc = wid & 1;
    const int m0 = blockIdx.y * 128, n0 = blockIdx.x * 64;

    const bf16* Ab = A + (size_t)blockIdx.z * sA;
    const bf16* Bb = Bm + (size_t)blockIdx.z * sB;

    const uint32_t a_lds0 = lds_off(&smem[0][0]);
    const uint32_t b_lds0 = a_lds0 + 128 * 64 * 2;
    const uint32_t bufstride = 192 * 64 * 2;

    auto stage = [&](int kt, int buf) {
#pragma unroll
        for (int h = 0; h < 4; ++h) {
            int it = tid + h * 256;
            int r = it >> 3, ch = it & 7;
            int sch = ch ^ (r & 7);
            g2l16(Ab + (size_t)(m0 + r) * K + kt * 64 + sch * 8,
                  a_lds0 + buf * bufstride + it * 16);
        }
#pragma unroll
        for (int h = 0; h < 2; ++h) {
            int it = tid + h * 256;
            int r = it >> 3, ch = it & 7;
            int sch = ch ^ (r & 7);
            g2l16(Bb + (size_t)(n0 + r) * K + kt * 64 + sch * 8,
                  b_lds0 + buf * bufstride + it * 16);
        }
    };

    f32x4 acc[4][2];
#pragma unroll
    for (int i = 0; i < 4; ++i)
#pragma unroll
        for (int j = 0; j < 2; ++j) { f32x4 z = {0.f,0.f,0.f,0.f}; acc[i][j] = z; }

    stage(0, 0);
    __syncthreads();

    const int nt = K >> 6;
    for (int t = 0; t < nt; ++t) {
        int buf = t & 1;
        if (t + 1 < nt) stage(t + 1, buf ^ 1);
        const bf16* As = &smem[buf][0];
        const bf16* Bs = &smem[buf][128 * 64];
#pragma unroll
        for (int s = 0; s < 2; ++s) {
            bf16x8 af[4], bfr[2];
#pragma unroll
            for (int mi = 0; mi < 4; ++mi) {
                int row = wr * 64 + mi * 16 + lr;
                int slot = (s * 4 + lg) ^ (row & 7);
                af[mi] = *(const bf16x8*)(As + row * 64 + slot * 8);
            }
#pragma unroll
            for (int ni = 0; ni < 2; ++ni) {
                int row = wc * 32 + ni * 16 + lr;
                int slot = (s * 4 + lg) ^ (row & 7);
                bfr[ni] = *(const bf16x8*)(Bs + row * 64 + slot * 8);
            }
#pragma unroll
            for (int mi = 0; mi < 4; ++mi)
#pragma unroll
                for (int ni = 0; ni < 2; ++ni)
                    acc[mi][ni] = __builtin_amdgcn_mfma_f32_16x16x32_bf16(
                        af[mi], bfr[ni], acc[mi][ni], 0, 0, 0);
        }
        __syncthreads();
    }

#pragma unroll
    for (int mi = 0; mi < 4; ++mi)
#pragma unroll
        for (int ni = 0; ni < 2; ++ni)
#pragma unroll
            for (int r = 0; r < 4; ++r) {
                int row = m0 + wr * 64 + mi * 16 + lg * 4 + r;
                int col = n0 + wc * 32 + ni * 16 + lr;
                float bv = (BIAS == 0) ? bias[row] : bias[col];
                float v = acc[mi][ni][r] + bv;
                if constexpr (OF32)
                    ((float*)Cv + (size_t)blockIdx.z * sC)[(size_t)row * Nn + col] = v;
                else
                    ((bf16*)Cv + (size_t)blockIdx.z * sC)[(size_t)row * Nn + col] = (bf16)v;
            }
}

// ---------------------------------------------------------------------------
// Attention v4 — 2-deep QK^T pipeline. qkv (Q,K) + vT -> aoT (B,C,N).
// 256 thr = 4 waves; wave owns 32 q-rows (subtiles A/B). Per iteration t:
//   stage(t+2) -> exp/P-write(t) -> vmcnt(4)+barrier -> QK^T(t+1) -> PV(t)
//   -> barrier
// so exp2 VALU work and the P LDS roundtrip overlap QK^T(t+1)'s MFMAs
// instead of serializing the MFMA pipe (attn was chain-bound, MfmaUtil 16%).
// K double-buffered (write 2 ahead at parity t&1: last read was iter t-1,
// behind a barrier). V triple-buffered mod 3 (PV(t) reads t%3 while t+2
// stages (t+2)%3). LDS 56 KB -> 2 blocks/CU at grid 512.
// ---------------------------------------------------------------------------
__global__ __launch_bounds__(256) void attn_k(
    const bf16* __restrict__ qkv, const bf16* __restrict__ vT,
    bf16* __restrict__ aoT)
{
    __shared__ bf16 Ks[2][4096];     // 16 KB
    __shared__ bf16 Vs[3][4096];     // 24 KB
    __shared__ bf16 pbuf[4][2048];   // 16 KB

    const int tid = threadIdx.x;
    const int lane = tid & 63, wid = tid >> 6;
    const int lr = lane & 15, lg = lane >> 4;
    const int bid = blockIdx.x;
    const int qt = bid >> 6, hb = bid & 63;
    const int b = hb >> 4, h = hb & 15;
    const int qrow0 = qt * 128 + wid * 32;
    const int hoff = h * 64;
    const bf16* qkvb = qkv + (size_t)b * (N_ * 3 * C_);
    const bf16* vTb  = vT + (size_t)b * MEG;

    bf16x8 qfA[2], qfB[2];
#pragma unroll
    for (int kk = 0; kk < 2; ++kk) {
        qfA[kk] = *(const bf16x8*)(qkvb + (size_t)(qrow0 + lr) * 3072 +
                                   hoff + kk * 32 + lg * 8);
        qfB[kk] = *(const bf16x8*)(qkvb + (size_t)(qrow0 + 16 + lr) * 3072 +
                                   hoff + kk * 32 + lg * 8);
#pragma unroll
        for (int j = 0; j < 8; ++j) {
            qfA[kk][j] = (bf16)((float)qfA[kk][j] * 0.18033688f);  // 0.125*log2e
            qfB[kk][j] = (bf16)((float)qfB[kk][j] * 0.18033688f);
        }
    }

    const uint32_t ks0 = lds_off(&Ks[0][0]);
    const uint32_t vs0 = lds_off(&Vs[0][0]);

    auto stageK = [&](int kt, int buf) {   // 2 g2l16 / thread
#pragma unroll
        for (int hh = 0; hh < 2; ++hh) {
            int it = tid + hh * 256;
            int key = it >> 3, ch = it & 7;
            int sch = ch ^ (key & 7);
            g2l16(qkvb + (size_t)(kt * 64 + key) * 3072 + C_ + hoff + sch * 8,
                  ks0 + buf * 8192 + it * 16);
        }
    };
    auto stageV = [&](int kt, int buf) {   // 2 g2l16 / thread
#pragma unroll
        for (int hh = 0; hh < 2; ++hh) {
            int it = tid + hh * 256;
            int d = it >> 3, ch = it & 7;
            int sch = ch ^ (d & 7);
            g2l16(vTb + (size_t)(hoff + d) * 1024 + kt * 64 + sch * 8,
                  vs0 + buf * 8192 + it * 16);
        }
    };

    // QK^T for tile kt (swapped operands): lane holds S[q=lr][key st*16+lg*4+r]
    auto qkt = [&](int kt, f32x4* SA, f32x4* SB) {
        const bf16* Kbase = &Ks[kt & 1][0];
        __builtin_amdgcn_s_setprio(1);
#pragma unroll
        for (int st = 0; st < 4; ++st) {
            f32x4 zA = {0.f, 0.f, 0.f, 0.f};
            f32x4 zB = {0.f, 0.f, 0.f, 0.f};
#pragma unroll
            for (int kk = 0; kk < 2; ++kk) {
                int row = st * 16 + lr;
                int slot = (kk * 4 + lg) ^ (row & 7);
                bf16x8 kf = *(const bf16x8*)(Kbase + row * 64 + slot * 8);
                zA = __builtin_amdgcn_mfma_f32_16x16x32_bf16(kf, qfA[kk], zA, 0, 0, 0);
                zB = __builtin_amdgcn_mfma_f32_16x16x32_bf16(kf, qfB[kk], zB, 0, 0, 0);
            }
            SA[st] = zA; SB[st] = zB;
        }
        __builtin_amdgcn_s_setprio(0);
    };

    float lsumA = 0.f, lsumB = 0.f;
    f32x4 oA[4], oB[4];
#pragma unroll
    for (int i = 0; i < 4; ++i) {
        f32x4 z = {0.f,0.f,0.f,0.f};
        oA[i] = z; oB[i] = z;
    }

    char* prowA = (char*)&pbuf[wid][0] + lr * 128;
    char* prowB = (char*)&pbuf[wid][0] + (16 + lr) * 128;
    const int swz = (lr & 7) << 4;

    // ---- prologue: tiles 0 and 1 staged; S(0) computed ----
    stageK(0, 0); stageV(0, 0);
    stageK(1, 1); stageV(1, 1);
    asm volatile("s_waitcnt vmcnt(4)" ::: "memory");   // tile0 landed
    __builtin_amdgcn_s_barrier();

    f32x4 sA[4], sB[4];
    qkt(0, sA, sB);
    __builtin_amdgcn_s_barrier();   // all waves done reading Ks[0] before stage(2) overwrites it

    for (int kt = 0; kt < 16; ++kt) {
        if (kt + 2 < 16) {
            stageK(kt + 2, kt & 1);          // (kt+2)&1 == kt&1
            stageV(kt + 2, (kt + 2) % 3);
        }

        // ---- exp2 + P-write for tile kt (uses S carried from last iter) ----
#pragma unroll
        for (int st = 0; st < 4; ++st) {
            bf16x4 wA, wB;
#pragma unroll
            for (int r = 0; r < 4; ++r) {
                float eA = __builtin_amdgcn_exp2f(sA[st][r]);
                float eB = __builtin_amdgcn_exp2f(sB[st][r]);
                wA[r] = (bf16)eA; lsumA += eA;
                wB[r] = (bf16)eB; lsumB += eB;
            }
            *(bf16x4*)(prowA + ((st * 32 + lg * 8) ^ swz)) = wA;
            *(bf16x4*)(prowB + ((st * 32 + lg * 8) ^ swz)) = wB;
        }

        // ---- next tile's QK^T (overlaps the P roundtrip & exp tail) ----
        f32x4 nA[4], nB[4];
        if (kt + 1 < 16) {
            if (kt + 2 < 16)
                asm volatile("s_waitcnt vmcnt(4)" ::: "memory");  // kt+1 landed, kt+2 in flight
            else
                asm volatile("s_waitcnt vmcnt(0)" ::: "memory");
            __builtin_amdgcn_s_barrier();
            qkt(kt + 1, nA, nB);
        }

        // ---- P A-fragments + PV for tile kt ----
        bf16x8 pfA[2], pfB[2];
        pfA[0] = *(const bf16x8*)(prowA + ((lg * 16) ^ swz));
        pfA[1] = *(const bf16x8*)(prowA + ((64 + lg * 16) ^ swz));
        pfB[0] = *(const bf16x8*)(prowB + ((lg * 16) ^ swz));
        pfB[1] = *(const bf16x8*)(prowB + ((64 + lg * 16) ^ swz));

        const bf16* Vbase = &Vs[kt % 3][0];
        __builtin_amdgcn_s_setprio(1);
#pragma unroll
        for (int dt = 0; dt < 4; ++dt) {
            int row = dt * 16 + lr;
            bf16x8 v0 = *(const bf16x8*)(Vbase + row * 64 + ((lg ^ (lr & 7)) * 8));
            bf16x8 v1 = *(const bf16x8*)(Vbase + row * 64 + (((4 + lg) ^ (lr & 7)) * 8));
            oA[dt] = __builtin_amdgcn_mfma_f32_16x16x32_bf16(pfA[0], v0, oA[dt], 0, 0, 0);
            oA[dt] = __builtin_amdgcn_mfma_f32_16x16x32_bf16(pfA[1], v1, oA[dt], 0, 0, 0);
            oB[dt] = __builtin_amdgcn_mfma_f32_16x16x32_bf16(pfB[0], v0, oB[dt], 0, 0, 0);
            oB[dt] = __builtin_amdgcn_mfma_f32_16x16x32_bf16(pfB[1], v1, oB[dt], 0, 0, 0);
        }
        __builtin_amdgcn_s_setprio(0);

        __builtin_amdgcn_s_barrier();   // V[kt%3]/K[(kt+1)&1] reads done before next iter's stages

#pragma unroll
        for (int i = 0; i < 4; ++i) { sA[i] = nA[i]; sB[i] = nB[i]; }
    }

    lsumA += __shfl_xor(lsumA, 16, 64);
    lsumA += __shfl_xor(lsumA, 32, 64);
    lsumB += __shfl_xor(lsumB, 16, 64);
    lsumB += __shfl_xor(lsumB, 32, 64);
    float rtotA = 1.0f / lsumA, rtotB = 1.0f / lsumB;
    float rcpoA[4], rcpoB[4];
#pragma unroll
    for (int r = 0; r < 4; ++r) {
        rcpoA[r] = __shfl(rtotA, lg * 4 + r, 64);
        rcpoB[r] = __shfl(rtotB, lg * 4 + r, 64);
    }

#pragma unroll
    for (int dt = 0; dt < 4; ++dt) {
        bf16x4 ovA, ovB;
#pragma unroll
        for (int r = 0; r < 4; ++r) {
            ovA[r] = (bf16)(oA[dt][r] * rcpoA[r]);
            ovB[r] = (bf16)(oB[dt][r] * rcpoB[r]);
        }
        size_t c = (size_t)b * C_ + hoff + dt * 16 + lr;
        *(bf16x4*)(aoT + c * N_ + qrow0 + lg * 4) = ovA;
        *(bf16x4*)(aoT + c * N_ + qrow0 + 16 + lg * 4) = ovB;
    }
}

// ---------------------------------------------------------------------------
// Workspace (bf16 elems; 26M = 52MB, proven budget):
//   xT   @  0M (4M)  gemm1 B; dead after gemm1 -> vT (written by gemm2)
//   Wq0b @  4M (1M)  dead after gemm1
//   Wq1b @  5M (3M)  dead after gemm2
//   Wp0b @  8M (1M)
//   Wp1b @  9M (1M)
//   y1   @ 10M (4M)  gemm1 out; dead after gemm2 -> aoT
//   y2   @ 14M (12M) qkv Q,K (V third unwritten); dead after attn -> z1
// ---------------------------------------------------------------------------
extern "C" void kernel_launch(void* const* d_in, const int* in_sizes, int n_in,
                              void* d_out, int out_size, void* d_ws, size_t ws_size,
                              hipStream_t stream) {
    (void)in_sizes; (void)n_in; (void)out_size; (void)ws_size;
    const float* x   = (const float*)d_in[0];
    const float* Wq0 = (const float*)d_in[1];
    const float* bq0 = (const float*)d_in[2];
    const float* Wq1 = (const float*)d_in[3];
    const float* bq1 = (const float*)d_in[4];
    const float* Wp0 = (const float*)d_in[5];
    const float* bp0 = (const float*)d_in[6];
    const float* Wp1 = (const float*)d_in[7];
    const float* bp1 = (const float*)d_in[8];

    bf16* ws   = (bf16*)d_ws;
    bf16* xT   = ws;
    bf16* Wq0b = ws + 4 * MEG;
    bf16* Wq1b = ws + 5 * MEG;
    bf16* Wp0b = ws + 8 * MEG;
    bf16* Wp1b = ws + 9 * MEG;
    bf16* y1   = ws + 10 * MEG;
    bf16* y2   = ws + 14 * MEG;
    bf16* vT   = xT;   // xT dead after gemm1; vT written by gemm2
    bf16* aoT  = y1;   // y1 dead after gemm2
    bf16* z1   = y2;   // y2 dead after attn
    float* outp = (float*)d_out;

    const long long s1M = (long long)N_ * C_;

    prep_k<<<dim3(4096), 256, 0, stream>>>(x, xT, Wq0, Wq0b, Wq1, Wq1b,
                                           Wp0, Wp0b, Wp1, Wp1b);

    // y1[b,m,c] = sum_n Wq0[m,n] xT[b,c,n] + bq0[m]   (512 blocks = 2/CU)
    gemm64_k<0, false><<<dim3(16, 8, 4), 256, 0, stream>>>(
        Wq0b, xT, bq0, y1, 1024, 1024, 1024, 0LL, s1M, s1M);
    // y2[(b,n),d] = sum_c y1[(b,n),c] Wq1[d,c] + bq1[d]; V third -> vT
    // (proven 2-phase 128x128, 768 blocks = 3/CU)
    gemm_k<1, false, true><<<dim3(24, 32, 1), 512, 0, stream>>>(
        y1, Wq1b, bq1, y2, vT, 4096, 3072, 1024, 0LL, 0LL, 0LL);
    // attention -> aoT (B,C,N)
    attn_k<<<dim3(512), 256, 0, stream>>>(y2, vT, aoT);
    // z1[b,m,c] = sum_n Wp0[m,n] aoT[b,c,n] + bp0[m]   (512 blocks = 2/CU)
    gemm64_k<0, false><<<dim3(16, 8, 4), 256, 0, stream>>>(
        Wp0b, aoT, bp0, z1, 1024, 1024, 1024, 0LL, s1M, s1M);
    // out[(b,n),d] = sum_c z1[(b,n),c] Wp1[d,c] + bp1[d] (512 blocks = 2/CU)
    gemm64_k<1, true><<<dim3(16, 32, 1), 256, 0, stream>>>(
        z1, Wp1b, bp1, outp, 4096, 1024, 1024, 0LL, 0LL, 0LL);
}